// Round 14
// baseline (295.389 us; speedup 1.0000x reference)
//
#include <hip/hip_runtime.h>
#include <stdint.h>

#define B_ 16
#define S1_ 2048
#define S2_ 2048
#define H_ 512

typedef short short8 __attribute__((ext_vector_type(8)));
typedef float f32x4 __attribute__((ext_vector_type(4)));
typedef long long2v __attribute__((ext_vector_type(2)));

__device__ __forceinline__ unsigned short f2bf(float f) {
  unsigned u = __builtin_bit_cast(unsigned, f);
  u += 0x7fffu + ((u >> 16) & 1u);          // round-to-nearest-even
  return (unsigned short)(u >> 16);
}
__device__ __forceinline__ float bf2f(unsigned short us) {
  return __builtin_bit_cast(float, (unsigned)us << 16);
}

__device__ __forceinline__ void gload_lds16(const void* g, void* l) {
  __builtin_amdgcn_global_load_lds((const __attribute__((address_space(1))) void*)g,
                                   (__attribute__((address_space(3))) void*)l,
                                   16, 0, 0);
}

// ---------------- prep: bf16/fp8 cast + reciprocal row-norm ----------------
// WB16: also write bf16 copy. fp8 (e4m3) stored PERMUTED within each 128-byte
// K-block: b' = lk*32 + s*8 + j for orig b = s*32 + lk*8 + j -- a lane's two
// 8B MFMA fragments become ADJACENT, enabling one 16B LDS read per fragment
// pair (16B granularity matches the XOR swizzle -> conflict-free).
// NOTE (r12 lesson): fp8 is ONLY valid for the QK^T operands -- unit-norm rows
// bound the ABSOLUTE score error (eps/sqrt(512)); P/V/FF have no absolute
// bound, their ~2-6% RELATIVE error does NOT average down and blows absmax.
template <int WB16>
__global__ __launch_bounds__(256) void k_cast(const float* __restrict__ x,
                                              unsigned short* __restrict__ y,
                                              unsigned char* __restrict__ y8,
                                              float* __restrict__ rn) {
  int row = blockIdx.x * 4 + (threadIdx.x >> 6);
  int l = threadIdx.x & 63;
  const f32x4* xr = (const f32x4*)(x + (size_t)row * H_) + l * 2;
  f32x4 a = xr[0], b = xr[1];
  float s = a[0]*a[0] + a[1]*a[1] + a[2]*a[2] + a[3]*a[3]
          + b[0]*b[0] + b[1]*b[1] + b[2]*b[2] + b[3]*b[3];
#pragma unroll
  for (int m = 1; m < 64; m <<= 1) s += __shfl_xor(s, m);
  if (l == 0) rn[row] = 1.0f / fmaxf(sqrtf(s), 1e-12f);
  if (WB16) {
    short8 o;
#pragma unroll
    for (int i = 0; i < 4; ++i) { o[i] = (short)f2bf(a[i]); o[4 + i] = (short)f2bf(b[i]); }
    *(short8*)(y + (size_t)row * H_ + l * 8) = o;
  }
  int p0 = __builtin_amdgcn_cvt_pk_fp8_f32(a[0], a[1], 0, false);
  p0 = __builtin_amdgcn_cvt_pk_fp8_f32(a[2], a[3], p0, true);
  int p1 = __builtin_amdgcn_cvt_pk_fp8_f32(b[0], b[1], 0, false);
  p1 = __builtin_amdgcn_cvt_pk_fp8_f32(b[2], b[3], p1, true);
  int2 pk = {p0, p1};
  // lane l covers orig bytes [l*8, l*8+8): t=l>>4 (128B block), s=(l>>2)&3, lk=l&3
  int poff = ((l >> 4) * 128) + ((l & 3) * 32) + (((l >> 2) & 3) * 8);
  *(int2*)(y8 + (size_t)row * H_ + poff) = pk;
}

// ---------------- prep: transpose+cast weights W[R][C] -> WT[C][R] bf16 ----------------
__global__ __launch_bounds__(256) void k_tw(const float* __restrict__ Wm,
                                            unsigned short* __restrict__ WT,
                                            int lgR, int C) {
  int i = blockIdx.x * 256 + threadIdx.x;     // over C*R outputs
  int R = 1 << lgR;
  int n = i >> lgR, k = i & (R - 1);
  WT[i] = f2bf(Wm[(size_t)k * C + n]);
}

// ---------------- prep: vt[b][h][s] = transpose(kn[b][s][h]) (bf16 -> bf16) ----------------
__global__ __launch_bounds__(256) void k_tvt(const unsigned short* __restrict__ kn,
                                             unsigned short* __restrict__ vt) {
  __shared__ unsigned short tile[64][72];
  int h0 = blockIdx.x * 64, s0 = blockIdx.y * 64, b = blockIdx.z;
  int t = threadIdx.x;
#pragma unroll
  for (int p = 0; p < 2; ++p) {
    int si = p * 32 + (t >> 3);
    int cj = (t & 7) * 8;
    short8 v = *(const short8*)(kn + ((size_t)(b * S2_ + s0 + si)) * H_ + h0 + cj);
#pragma unroll
    for (int x = 0; x < 8; ++x) tile[si][cj + x] = (unsigned short)v[x];
  }
  __syncthreads();
#pragma unroll
  for (int p = 0; p < 2; ++p) {
    int ho = p * 32 + (t >> 3);
    int sx = (t & 7) * 8;
    short8 o;
#pragma unroll
    for (int x = 0; x < 8; ++x) o[x] = (short)tile[sx + x][ho];
    *(short8*)(vt + ((size_t)(b * H_ + h0 + ho)) * S2_ + s0 + sx) = o;
  }
}

// ---------------- MFMA GEMM: 128-row tile, 4 waves, single-buf 32 KiB LDS ----
// Proven structure: stage -> vmcnt(0) -> barrier -> compute -> barrier; high
// blocks/CU residency + cross-block TLP hides staging latency (r3/r5: anything
// that cuts residency loses; r9: pass2 at 2 blk/CU was the slowest dispatch).
// FP8=1: A/B fp8 e4m3 in (s,lk)-permuted layout (see k_cast), BK=128; reads
// are short8 derefs anchored by an empty asm "+v" so the 128-bit value must
// materialize whole -> SROA can't split the load into 2x ds_read_b64 (the
// r11/r13 residual 4.19M-conflict cause: 8B reads vs 16B XOR granule).
// SWZ: XCD swizzle; ON for pass2/FF (panel L2 locality), OFF for pass1.
// MODE 0: FF1 relu(acc+bias) bf16 | MODE 1: FF2 acc+bias bf16
// MODE 2: P=exp(acc*rq[m]*rk[n]-1)*mask bf16 (no rowsum: LN1 row-scale-inv)
// MODE 3: acc bf16
template <int MODE, int SWZ, int FP8>
__global__ __launch_bounds__(256, 2) void k_gemm(
    const void* __restrict__ A, const void* __restrict__ BT,
    const float* __restrict__ bias, const int* __restrict__ mask,
    const float* __restrict__ rq, const float* __restrict__ rk,
    void* __restrict__ out,
    int M, int N, int K, long sAbytes, long sBbytes, long sOut) {
  __shared__ char lA[16384];
  __shared__ char lB[16384];

  int bx, by, z;
  if (SWZ) {
    const int gx = gridDim.x, gy = gridDim.y;
    const int nwg = gx * gy * (int)gridDim.z;
    int orig = ((int)blockIdx.z * gy + (int)blockIdx.y) * gx + (int)blockIdx.x;
    int swzid = ((nwg & 7) == 0) ? ((orig & 7) * (nwg >> 3) + (orig >> 3)) : orig;
    z = swzid / (gx * gy);
    int rem = swzid - z * (gx * gy);
    by = rem / gx;
    bx = rem - by * gx;
  } else {
    bx = blockIdx.x; by = blockIdx.y; z = blockIdx.z;
  }

  const int w = threadIdx.x >> 6, l = threadIdx.x & 63;
  const int lr = l & 15, lk = l >> 4;
  const int m0 = by * 128, n0 = bx * 128;
  const int wm = (w >> 1) * 64, wn = (w & 1) * 64;

  // staging: chunk c=j*4+w covers rows 8c..8c+7 (128 B each); lane l covers
  // row 8c+(l>>3), 16 source bytes at col ((l&7)*16) ^ XOR-swizzle; dest linear.
  const size_t rowbytes = (size_t)K * (FP8 ? 1 : 2);
  const int srow = l >> 3;
  const int lswz = ((l & 7) * 16) ^ ((srow & 7) << 4);
  const char* pA = (const char*)A + (size_t)z * sAbytes + (size_t)(m0 + w * 8 + srow) * rowbytes + lswz;
  const char* pB = (const char*)BT + (size_t)z * sBbytes + (size_t)(n0 + w * 8 + srow) * rowbytes + lswz;
  const size_t rstep = rowbytes * 32;   // 32 rows per j-step

  f32x4 acc[4][4];
#pragma unroll
  for (int i = 0; i < 4; ++i)
#pragma unroll
    for (int j = 0; j < 4; ++j) acc[i][j] = (f32x4){0.f, 0.f, 0.f, 0.f};

  const int NT = K >> (FP8 ? 7 : 6);

#pragma unroll 1
  for (int t = 0; t < NT; ++t) {
    const size_t kb = (size_t)t * 128;   // 128 B per tile step in both dtypes
#pragma unroll
    for (int j = 0; j < 4; ++j) {
      gload_lds16(pA + j * rstep + kb, lA + (j * 4 + w) * 1024);
      gload_lds16(pB + j * rstep + kb, lB + (j * 4 + w) * 1024);
    }
    asm volatile("s_waitcnt vmcnt(0)" ::: "memory");
    __syncthreads();
    if (FP8) {
      // permuted layout: one 16B read at (lk*32 + s2*16) ^ swz holds the
      // s=2*s2 and s=2*s2+1 fragments; 16B unit x=(lk*2+s2)^(row&7) spans all
      // 8 slots per quarter-wave -> conflict-free iff emitted as ds_read_b128.
#pragma unroll
      for (int s2 = 0; s2 < 2; ++s2) {
        long2v af[4], bf[4];
#pragma unroll
        for (int mi = 0; mi < 4; ++mi) {
          int row = wm + mi * 16 + lr;
          short8 tmp = *(const short8*)(lA + row * 128 + ((lk * 32 + s2 * 16) ^ ((row & 7) << 4)));
          asm volatile("" : "+v"(tmp));   // anchor whole 128b value -> one ds_read_b128
          af[mi] = __builtin_bit_cast(long2v, tmp);
        }
#pragma unroll
        for (int ni = 0; ni < 4; ++ni) {
          int row = wn + ni * 16 + lr;
          short8 tmp = *(const short8*)(lB + row * 128 + ((lk * 32 + s2 * 16) ^ ((row & 7) << 4)));
          asm volatile("" : "+v"(tmp));   // anchor whole 128b value -> one ds_read_b128
          bf[ni] = __builtin_bit_cast(long2v, tmp);
        }
#pragma unroll
        for (int mi = 0; mi < 4; ++mi)
#pragma unroll
          for (int ni = 0; ni < 4; ++ni) {
            acc[mi][ni] = __builtin_amdgcn_mfma_f32_16x16x32_fp8_fp8(af[mi].x, bf[ni].x, acc[mi][ni], 0, 0, 0);
            acc[mi][ni] = __builtin_amdgcn_mfma_f32_16x16x32_fp8_fp8(af[mi].y, bf[ni].y, acc[mi][ni], 0, 0, 0);
          }
      }
    } else {
      const unsigned short* As = (const unsigned short*)lA;
      const unsigned short* Bs = (const unsigned short*)lB;
#pragma unroll
      for (int s = 0; s < 2; ++s) {
        short8 af[4], bf[4];
#pragma unroll
        for (int mi = 0; mi < 4; ++mi) {
          int row = wm + mi * 16 + lr;
          af[mi] = *(const short8*)(As + row * 64 + ((s * 32 + lk * 8) ^ ((row & 7) << 3)));
        }
#pragma unroll
        for (int ni = 0; ni < 4; ++ni) {
          int row = wn + ni * 16 + lr;
          bf[ni] = *(const short8*)(Bs + row * 64 + ((s * 32 + lk * 8) ^ ((row & 7) << 3)));
        }
#pragma unroll
        for (int mi = 0; mi < 4; ++mi)
#pragma unroll
          for (int ni = 0; ni < 4; ++ni)
            acc[mi][ni] = __builtin_amdgcn_mfma_f32_16x16x32_bf16(af[mi], bf[ni], acc[mi][ni], 0, 0, 0);
      }
    }
    __syncthreads();
  }

  if (MODE == 2) {
    float rqv[4][4], rkv[4], mv[4];
#pragma unroll
    for (int mi = 0; mi < 4; ++mi)
#pragma unroll
      for (int r = 0; r < 4; ++r)
        rqv[mi][r] = rq[(size_t)z * M + m0 + wm + mi * 16 + lk * 4 + r];
#pragma unroll
    for (int ni = 0; ni < 4; ++ni) {
      int gn = n0 + wn + ni * 16 + lr;
      rkv[ni] = rk[(size_t)z * N + gn];
      mv[ni] = (mask[(size_t)z * N + gn] != 0) ? 1.0f : 0.0f;
    }
#pragma unroll
    for (int mi = 0; mi < 4; ++mi)
#pragma unroll
      for (int ni = 0; ni < 4; ++ni) {
        int gn = n0 + wn + ni * 16 + lr;
#pragma unroll
        for (int r = 0; r < 4; ++r) {
          int gm = m0 + wm + mi * 16 + lk * 4 + r;
          float p = __expf(acc[mi][ni][r] * rqv[mi][r] * rkv[ni] - 1.0f) * mv[ni];
          ((unsigned short*)out)[(size_t)z * sOut + (size_t)gm * N + gn] = f2bf(p);
        }
      }
  } else if (MODE == 3) {
#pragma unroll
    for (int mi = 0; mi < 4; ++mi)
#pragma unroll
      for (int r = 0; r < 4; ++r) {
        int gm = m0 + wm + mi * 16 + lk * 4 + r;
#pragma unroll
        for (int ni = 0; ni < 4; ++ni) {
          int gn = n0 + wn + ni * 16 + lr;
          ((unsigned short*)out)[(size_t)z * sOut + (size_t)gm * N + gn] = f2bf(acc[mi][ni][r]);
        }
      }
  } else {
#pragma unroll
    for (int mi = 0; mi < 4; ++mi)
#pragma unroll
      for (int ni = 0; ni < 4; ++ni) {
        int gn = n0 + wn + ni * 16 + lr;
        float bs = bias[gn];
#pragma unroll
        for (int r = 0; r < 4; ++r) {
          int gm = m0 + wm + mi * 16 + lk * 4 + r;
          float v = acc[mi][ni][r] + bs;
          if (MODE == 0) v = fmaxf(v, 0.f);
          ((unsigned short*)out)[(size_t)gm * N + gn] = f2bf(v);
        }
      }
  }
}

// ---------------- LN1: nattn = LN(O)*g+b (bf16); O unnormalized (LN scale-inv) ----
__global__ __launch_bounds__(256) void k_ln1(const unsigned short* __restrict__ O,
                                             const float* __restrict__ g,
                                             const float* __restrict__ bvec,
                                             unsigned short* __restrict__ nattn) {
  int row = blockIdx.x * 4 + (threadIdx.x >> 6);
  int l = threadIdx.x & 63;
  size_t base = (size_t)row * H_ + l * 8;
  short8 ov = *(const short8*)(O + base);
  float x[8];
#pragma unroll
  for (int i = 0; i < 8; ++i) x[i] = bf2f((unsigned short)ov[i]);
  float s = 0.f, q = 0.f;
#pragma unroll
  for (int i = 0; i < 8; ++i) { s += x[i]; q += x[i] * x[i]; }
#pragma unroll
  for (int m = 1; m < 64; m <<= 1) { s += __shfl_xor(s, m); q += __shfl_xor(q, m); }
  float mean = s * (1.f / 512.f);
  float var = q * (1.f / 512.f) - mean * mean;
  float rstd = rsqrtf(var + 1e-6f);
  f32x4 g0 = *(const f32x4*)(g + l * 8), g1v = *(const f32x4*)(g + l * 8 + 4);
  f32x4 b0 = *(const f32x4*)(bvec + l * 8), b1v = *(const f32x4*)(bvec + l * 8 + 4);
  short8 no;
#pragma unroll
  for (int i = 0; i < 4; ++i) {
    no[i]     = (short)f2bf((x[i] - mean) * rstd * g0[i] + b0[i]);
    no[4 + i] = (short)f2bf((x[4 + i] - mean) * rstd * g1v[i] + b1v[i]);
  }
  *(short8*)(nattn + base) = no;
}

// ---------------- LN2(ff bf16) + nattn + text1 -> out ----------------
// TB=1: residual text1 read as bf16 (t1b) -- saves 96 MiB of HBM read.
template <int TB>
__global__ __launch_bounds__(256) void k_ln2(const unsigned short* __restrict__ ff,
                                             const unsigned short* __restrict__ nattn,
                                             const float* __restrict__ text1,
                                             const unsigned short* __restrict__ t1b,
                                             const float* __restrict__ g2,
                                             const float* __restrict__ bb2,
                                             float* __restrict__ out) {
  int row = blockIdx.x * 4 + (threadIdx.x >> 6);
  int l = threadIdx.x & 63;
  size_t base = (size_t)row * H_ + l * 8;
  short8 fv = *(const short8*)(ff + base);
  float x[8];
#pragma unroll
  for (int i = 0; i < 8; ++i) x[i] = bf2f((unsigned short)fv[i]);
  float s = 0.f, q = 0.f;
#pragma unroll
  for (int i = 0; i < 8; ++i) { s += x[i]; q += x[i] * x[i]; }
#pragma unroll
  for (int m = 1; m < 64; m <<= 1) { s += __shfl_xor(s, m); q += __shfl_xor(q, m); }
  float mean = s * (1.f / 512.f);
  float var = q * (1.f / 512.f) - mean * mean;
  float rstd = rsqrtf(var + 1e-6f);
  f32x4 g0 = *(const f32x4*)(g2 + l * 8), g1v = *(const f32x4*)(g2 + l * 8 + 4);
  f32x4 b0 = *(const f32x4*)(bb2 + l * 8), b1v = *(const f32x4*)(bb2 + l * 8 + 4);
  short8 nv = *(const short8*)(nattn + base);
  f32x4 t0, t1;
  if (TB) {
    short8 tv = *(const short8*)(t1b + base);
#pragma unroll
    for (int i = 0; i < 4; ++i) { t0[i] = bf2f((unsigned short)tv[i]); t1[i] = bf2f((unsigned short)tv[4 + i]); }
  } else {
    t0 = *(const f32x4*)(text1 + base);
    t1 = *(const f32x4*)(text1 + base + 4);
  }
  f32x4 o0, o1;
#pragma unroll
  for (int i = 0; i < 4; ++i) {
    o0[i] = (x[i] - mean) * rstd * g0[i] + b0[i] + bf2f((unsigned short)nv[i]) + t0[i];
    o1[i] = (x[4 + i] - mean) * rstd * g1v[i] + b1v[i] + bf2f((unsigned short)nv[4 + i]) + t1[i];
  }
  *(f32x4*)(out + base) = o0;
  *(f32x4*)(out + base + 4) = o1;
}

extern "C" void kernel_launch(void* const* d_in, const int* in_sizes, int n_in,
                              void* d_out, int out_size, void* d_ws, size_t ws_size,
                              hipStream_t stream) {
  const float* text1 = (const float*)d_in[0];
  const float* text2 = (const float*)d_in[1];
  // d_in[2] = text1_mask (unused by reference output)
  const int* mask2 = (const int*)d_in[3];
  const float* W1 = (const float*)d_in[4];
  const float* b1 = (const float*)d_in[5];
  const float* W2 = (const float*)d_in[6];
  const float* b2 = (const float*)d_in[7];
  const float* g1 = (const float*)d_in[8];
  const float* bb1 = (const float*)d_in[9];
  const float* g2 = (const float*)d_in[10];
  const float* bb2 = (const float*)d_in[11];

  const size_t MiB = 1024ull * 1024ull;
  char* ws = (char*)d_ws;
  // ---- layout (base footprint 196 MiB; optional t1b extends to 228 MiB) ----
  unsigned short* W1T   = (unsigned short*)(ws + 0 * MiB);          // 1 MiB
  unsigned short* W2T   = (unsigned short*)(ws + 1 * MiB);          // 1 MiB
  float*          rq    = (float*)(ws + 2 * MiB);                   // 128 KiB
  float*          rk    = (float*)(ws + 2 * MiB + 256 * 1024);      // 128 KiB
  unsigned char*  qn8   = (unsigned char*)(ws + 4 * MiB);     // 16 MiB [4,20)
  unsigned char*  kn8   = (unsigned char*)(ws + 20 * MiB);    // 16 MiB [20,36)
  unsigned short* kn    = (unsigned short*)(ws + 36 * MiB);   // 32 MiB [36,68): dead after k_tvt
  unsigned short* vt    = (unsigned short*)(ws + 164 * MiB);  // 32 MiB [164,196): dead after pass2
  unsigned short* P     = (unsigned short*)(ws + 36 * MiB);   // 128 MiB [36,164) over kn (dead);
                                                              //   all 16 batches, dead after pass2
  unsigned short* O     = (unsigned short*)(ws + 4 * MiB);    // 32 MiB [4,36) over qn8+kn8 (dead
                                                              //   after pass1; pass2 runs later)
  // aliases (stream-order lifetimes; each span checked against later readers):
  unsigned short* nattn = (unsigned short*)(ws + 100 * MiB);  // [100,132) over P-mid (dead after
                                                              //   pass2); live LN1 -> LN2; nothing
                                                              //   writes [100,132) in between (FF1
                                                              //   -> [132,196), FF2 -> [36,68)).
  unsigned short* hbuf  = (unsigned short*)(ws + 132 * MiB);  // [132,196) over P-upper + vt (both
                                                              //   dead after pass2)
  unsigned short* ffb   = (unsigned short*)(ws + 36 * MiB);   // [36,68) over P-lower (dead); NOT
                                                              //   overlapping nattn (round-4 bug)
  unsigned short* t1b   = (unsigned short*)(ws + 196 * MiB);  // 32 MiB [196,228): ONLY if ws_size
                                                              //   allows; live k_cast -> LN2, no
                                                              //   other writer touches >=196 MiB.
  const bool useT1b = (ws_size >= 228 * MiB);                 // deterministic per-run
  float* outp = (float*)d_out;

  if (useT1b)
    k_cast<1><<<dim3(B_ * S1_ / 4), 256, 0, stream>>>(text1, t1b, qn8, rq);
  else
    k_cast<0><<<dim3(B_ * S1_ / 4), 256, 0, stream>>>(text1, nullptr, qn8, rq);
  k_cast<1><<<dim3(B_ * S2_ / 4), 256, 0, stream>>>(text2, kn, kn8, rk);
  k_tw<<<dim3(512 * 1024 / 256), 256, 0, stream>>>(W1, W1T, 9, 1024);
  k_tw<<<dim3(512 * 1024 / 256), 256, 0, stream>>>(W2, W2T, 10, 512);
  k_tvt<<<dim3(H_ / 64, S2_ / 64, B_), 256, 0, stream>>>(kn, vt);

  // pass1 (fp8 permuted, BK=128), all 16 batches: P = exp((q8@k8^T)*rq*rk - 1)*mask [SWZ=0]
  k_gemm<2, 0, 1><<<dim3(S2_ / 128, S1_ / 128, B_), 256, 0, stream>>>(
      qn8, kn8, nullptr, mask2, rq, rk,
      P, S1_, S2_, H_, (long)S1_ * H_, (long)S2_ * H_, (long)S1_ * S2_);
  // pass2 (bf16), all 16 batches: O = P @ V (unnormalized; LN1 washes row scale)
  // grid 4x16x16 = 1024 blocks = 4 blk/CU (r9: 512 blocks = 2/CU was the bottleneck)
  k_gemm<3, 1, 0><<<dim3(H_ / 128, S1_ / 128, B_), 256, 0, stream>>>(
      P, vt, nullptr, nullptr, nullptr, nullptr,
      O, S1_, H_, S2_, (long)S1_ * S2_ * 2, (long)H_ * S2_ * 2, (long)S1_ * H_);

  k_ln1<<<dim3(B_ * S1_ / 4), 256, 0, stream>>>(O, g1, bb1, nattn);
  k_gemm<0, 1, 0><<<dim3(1024 / 128, 32768 / 128, 1), 256, 0, stream>>>(
      nattn, W1T, b1, nullptr, nullptr, nullptr, hbuf, 32768, 1024, 512, 0, 0, 0);
  k_gemm<1, 1, 0><<<dim3(512 / 128, 32768 / 128, 1), 256, 0, stream>>>(
      hbuf, W2T, b2, nullptr, nullptr, nullptr, ffb, 32768, 512, 1024, 0, 0, 0);
  if (useT1b)
    k_ln2<1><<<dim3(32768 / 4), 256, 0, stream>>>(ffb, nattn, nullptr, t1b, g2, bb2, outp);
  else
    k_ln2<0><<<dim3(32768 / 4), 256, 0, stream>>>(ffb, nattn, text1, nullptr, g2, bb2, outp);
}

// Round 15
// 287.973 us; speedup vs baseline: 1.0258x; 1.0258x over previous
//
#include <hip/hip_runtime.h>
#include <stdint.h>

#define B_ 16
#define S1_ 2048
#define S2_ 2048
#define H_ 512

typedef short short8 __attribute__((ext_vector_type(8)));
typedef float f32x4 __attribute__((ext_vector_type(4)));
typedef long long2v __attribute__((ext_vector_type(2)));

__device__ __forceinline__ unsigned short f2bf(float f) {
  unsigned u = __builtin_bit_cast(unsigned, f);
  u += 0x7fffu + ((u >> 16) & 1u);          // round-to-nearest-even
  return (unsigned short)(u >> 16);
}
__device__ __forceinline__ float bf2f(unsigned short us) {
  return __builtin_bit_cast(float, (unsigned)us << 16);
}

__device__ __forceinline__ void gload_lds16(const void* g, void* l) {
  __builtin_amdgcn_global_load_lds((const __attribute__((address_space(1))) void*)g,
                                   (__attribute__((address_space(3))) void*)l,
                                   16, 0, 0);
}

// ---------------- prep: fp8(normalized, perm) + optional raw bf16 copy ----------------
// fp8 (e4m3) stores x/||x|| DIRECTLY (norm folded into quantization -- qn8/kn8
// are separate buffers from kn, which stays raw bf16 as the V source). Score
// abs-error unchanged vs raw-fp8 + epilogue-scale: unit-norm rows bound the
// absolute error either way (r12 lesson: fp8 is ONLY valid where an absolute
// bound exists; P/V/FF relative error does NOT average down).
// fp8 stored PERMUTED within each 128-byte K-block: b' = lk*32 + s*8 + j for
// orig b = s*32 + lk*8 + j -- a lane's two 8B MFMA fragments become adjacent
// (16B granularity matches the GEMM's XOR swizzle).
template <int WB16>
__global__ __launch_bounds__(256) void k_cast(const float* __restrict__ x,
                                              unsigned short* __restrict__ y,
                                              unsigned char* __restrict__ y8) {
  int row = blockIdx.x * 4 + (threadIdx.x >> 6);
  int l = threadIdx.x & 63;
  const f32x4* xr = (const f32x4*)(x + (size_t)row * H_) + l * 2;
  f32x4 a = xr[0], b = xr[1];
  float s = a[0]*a[0] + a[1]*a[1] + a[2]*a[2] + a[3]*a[3]
          + b[0]*b[0] + b[1]*b[1] + b[2]*b[2] + b[3]*b[3];
#pragma unroll
  for (int m = 1; m < 64; m <<= 1) s += __shfl_xor(s, m);
  float sc = 1.0f / fmaxf(sqrtf(s), 1e-12f);   // all lanes hold the full sum
  if (WB16) {
    short8 o;
#pragma unroll
    for (int i = 0; i < 4; ++i) { o[i] = (short)f2bf(a[i]); o[4 + i] = (short)f2bf(b[i]); }
    *(short8*)(y + (size_t)row * H_ + l * 8) = o;
  }
  int p0 = __builtin_amdgcn_cvt_pk_fp8_f32(a[0] * sc, a[1] * sc, 0, false);
  p0 = __builtin_amdgcn_cvt_pk_fp8_f32(a[2] * sc, a[3] * sc, p0, true);
  int p1 = __builtin_amdgcn_cvt_pk_fp8_f32(b[0] * sc, b[1] * sc, 0, false);
  p1 = __builtin_amdgcn_cvt_pk_fp8_f32(b[2] * sc, b[3] * sc, p1, true);
  int2 pk = {p0, p1};
  // lane l covers orig bytes [l*8, l*8+8): t=l>>4 (128B block), s=(l>>2)&3, lk=l&3
  int poff = ((l >> 4) * 128) + ((l & 3) * 32) + (((l >> 2) & 3) * 8);
  *(int2*)(y8 + (size_t)row * H_ + poff) = pk;
}

// ---------------- prep: transpose+cast weights W[R][C] -> WT[C][R] bf16 ----------------
__global__ __launch_bounds__(256) void k_tw(const float* __restrict__ Wm,
                                            unsigned short* __restrict__ WT,
                                            int lgR, int C) {
  int i = blockIdx.x * 256 + threadIdx.x;     // over C*R outputs
  int R = 1 << lgR;
  int n = i >> lgR, k = i & (R - 1);
  WT[i] = f2bf(Wm[(size_t)k * C + n]);
}

// ---------------- prep: vt[b][h][s] = transpose(kn[b][s][h]) (bf16 -> bf16) ----------------
__global__ __launch_bounds__(256) void k_tvt(const unsigned short* __restrict__ kn,
                                             unsigned short* __restrict__ vt) {
  __shared__ unsigned short tile[64][72];
  int h0 = blockIdx.x * 64, s0 = blockIdx.y * 64, b = blockIdx.z;
  int t = threadIdx.x;
#pragma unroll
  for (int p = 0; p < 2; ++p) {
    int si = p * 32 + (t >> 3);
    int cj = (t & 7) * 8;
    short8 v = *(const short8*)(kn + ((size_t)(b * S2_ + s0 + si)) * H_ + h0 + cj);
#pragma unroll
    for (int x = 0; x < 8; ++x) tile[si][cj + x] = (unsigned short)v[x];
  }
  __syncthreads();
#pragma unroll
  for (int p = 0; p < 2; ++p) {
    int ho = p * 32 + (t >> 3);
    int sx = (t & 7) * 8;
    short8 o;
#pragma unroll
    for (int x = 0; x < 8; ++x) o[x] = (short)tile[sx + x][ho];
    *(short8*)(vt + ((size_t)(b * H_ + h0 + ho)) * S2_ + s0 + sx) = o;
  }
}

// ---------------- MFMA GEMM: 128-row tile, 4 waves, single-buf 32 KiB LDS ----
// Proven structure: stage -> vmcnt(0) -> barrier -> compute -> barrier; high
// blocks/CU residency + cross-block TLP hides staging latency (r3/r5: anything
// that cuts residency loses; r9: pass2 at 2 blk/CU was the slowest dispatch).
// FP8=1: A/B fp8 e4m3 (pre-normalized) in (s,lk)-permuted layout, BK=128.
// Residual 4.19M bank conflicts on the fp8 ds_read (compiler splits the 16B
// read into 2x b64; 3 fix attempts failed; ~2-3us hidden cost -- ACCEPTED).
// SWZ: XCD swizzle; ON for pass2/FF (panel L2 locality), OFF for pass1.
// MODE 0: FF1 relu(acc+bias) bf16 | MODE 1: FF2 acc+bias bf16
// MODE 2: P=exp(acc-1)*mask bf16 (no rowsum: LN1 row-scale-inv) | MODE 3: acc bf16
template <int MODE, int SWZ, int FP8>
__global__ __launch_bounds__(256, 2) void k_gemm(
    const void* __restrict__ A, const void* __restrict__ BT,
    const float* __restrict__ bias, const int* __restrict__ mask,
    void* __restrict__ out,
    int M, int N, int K, long sAbytes, long sBbytes, long sOut) {
  __shared__ char lA[16384];
  __shared__ char lB[16384];

  int bx, by, z;
  if (SWZ) {
    const int gx = gridDim.x, gy = gridDim.y;
    const int nwg = gx * gy * (int)gridDim.z;
    int orig = ((int)blockIdx.z * gy + (int)blockIdx.y) * gx + (int)blockIdx.x;
    int swzid = ((nwg & 7) == 0) ? ((orig & 7) * (nwg >> 3) + (orig >> 3)) : orig;
    z = swzid / (gx * gy);
    int rem = swzid - z * (gx * gy);
    by = rem / gx;
    bx = rem - by * gx;
  } else {
    bx = blockIdx.x; by = blockIdx.y; z = blockIdx.z;
  }

  const int w = threadIdx.x >> 6, l = threadIdx.x & 63;
  const int lr = l & 15, lk = l >> 4;
  const int m0 = by * 128, n0 = bx * 128;
  const int wm = (w >> 1) * 64, wn = (w & 1) * 64;

  // staging: chunk c=j*4+w covers rows 8c..8c+7 (128 B each); lane l covers
  // row 8c+(l>>3), 16 source bytes at col ((l&7)*16) ^ XOR-swizzle; dest linear.
  const size_t rowbytes = (size_t)K * (FP8 ? 1 : 2);
  const int srow = l >> 3;
  const int lswz = ((l & 7) * 16) ^ ((srow & 7) << 4);
  const char* pA = (const char*)A + (size_t)z * sAbytes + (size_t)(m0 + w * 8 + srow) * rowbytes + lswz;
  const char* pB = (const char*)BT + (size_t)z * sBbytes + (size_t)(n0 + w * 8 + srow) * rowbytes + lswz;
  const size_t rstep = rowbytes * 32;   // 32 rows per j-step

  f32x4 acc[4][4];
#pragma unroll
  for (int i = 0; i < 4; ++i)
#pragma unroll
    for (int j = 0; j < 4; ++j) acc[i][j] = (f32x4){0.f, 0.f, 0.f, 0.f};

  const int NT = K >> (FP8 ? 7 : 6);

#pragma unroll 1
  for (int t = 0; t < NT; ++t) {
    const size_t kb = (size_t)t * 128;   // 128 B per tile step in both dtypes
#pragma unroll
    for (int j = 0; j < 4; ++j) {
      gload_lds16(pA + j * rstep + kb, lA + (j * 4 + w) * 1024);
      gload_lds16(pB + j * rstep + kb, lB + (j * 4 + w) * 1024);
    }
    asm volatile("s_waitcnt vmcnt(0)" ::: "memory");
    __syncthreads();
    if (FP8) {
      // permuted layout: one 16B slot at (lk*32 + s2*16) ^ swz holds the
      // s=2*s2 and s=2*s2+1 fragments.
#pragma unroll
      for (int s2 = 0; s2 < 2; ++s2) {
        long2v af[4], bf[4];
#pragma unroll
        for (int mi = 0; mi < 4; ++mi) {
          int row = wm + mi * 16 + lr;
          short8 tmp = *(const short8*)(lA + row * 128 + ((lk * 32 + s2 * 16) ^ ((row & 7) << 4)));
          af[mi] = __builtin_bit_cast(long2v, tmp);
        }
#pragma unroll
        for (int ni = 0; ni < 4; ++ni) {
          int row = wn + ni * 16 + lr;
          short8 tmp = *(const short8*)(lB + row * 128 + ((lk * 32 + s2 * 16) ^ ((row & 7) << 4)));
          bf[ni] = __builtin_bit_cast(long2v, tmp);
        }
#pragma unroll
        for (int mi = 0; mi < 4; ++mi)
#pragma unroll
          for (int ni = 0; ni < 4; ++ni) {
            acc[mi][ni] = __builtin_amdgcn_mfma_f32_16x16x32_fp8_fp8(af[mi].x, bf[ni].x, acc[mi][ni], 0, 0, 0);
            acc[mi][ni] = __builtin_amdgcn_mfma_f32_16x16x32_fp8_fp8(af[mi].y, bf[ni].y, acc[mi][ni], 0, 0, 0);
          }
      }
    } else {
      const unsigned short* As = (const unsigned short*)lA;
      const unsigned short* Bs = (const unsigned short*)lB;
#pragma unroll
      for (int s = 0; s < 2; ++s) {
        short8 af[4], bf[4];
#pragma unroll
        for (int mi = 0; mi < 4; ++mi) {
          int row = wm + mi * 16 + lr;
          af[mi] = *(const short8*)(As + row * 64 + ((s * 32 + lk * 8) ^ ((row & 7) << 3)));
        }
#pragma unroll
        for (int ni = 0; ni < 4; ++ni) {
          int row = wn + ni * 16 + lr;
          bf[ni] = *(const short8*)(Bs + row * 64 + ((s * 32 + lk * 8) ^ ((row & 7) << 3)));
        }
#pragma unroll
        for (int mi = 0; mi < 4; ++mi)
#pragma unroll
          for (int ni = 0; ni < 4; ++ni)
            acc[mi][ni] = __builtin_amdgcn_mfma_f32_16x16x32_bf16(af[mi], bf[ni], acc[mi][ni], 0, 0, 0);
      }
    }
    __syncthreads();
  }

  if (MODE == 2) {
    float mv[4];
#pragma unroll
    for (int ni = 0; ni < 4; ++ni) {
      int gn = n0 + wn + ni * 16 + lr;
      mv[ni] = (mask[(size_t)z * N + gn] != 0) ? 1.0f : 0.0f;
    }
#pragma unroll
    for (int mi = 0; mi < 4; ++mi)
#pragma unroll
      for (int ni = 0; ni < 4; ++ni) {
        int gn = n0 + wn + ni * 16 + lr;
#pragma unroll
        for (int r = 0; r < 4; ++r) {
          int gm = m0 + wm + mi * 16 + lk * 4 + r;
          float p = __expf(acc[mi][ni][r] - 1.0f) * mv[ni];
          ((unsigned short*)out)[(size_t)z * sOut + (size_t)gm * N + gn] = f2bf(p);
        }
      }
  } else if (MODE == 3) {
#pragma unroll
    for (int mi = 0; mi < 4; ++mi)
#pragma unroll
      for (int r = 0; r < 4; ++r) {
        int gm = m0 + wm + mi * 16 + lk * 4 + r;
#pragma unroll
        for (int ni = 0; ni < 4; ++ni) {
          int gn = n0 + wn + ni * 16 + lr;
          ((unsigned short*)out)[(size_t)z * sOut + (size_t)gm * N + gn] = f2bf(acc[mi][ni][r]);
        }
      }
  } else {
#pragma unroll
    for (int mi = 0; mi < 4; ++mi)
#pragma unroll
      for (int ni = 0; ni < 4; ++ni) {
        int gn = n0 + wn + ni * 16 + lr;
        float bs = bias[gn];
#pragma unroll
        for (int r = 0; r < 4; ++r) {
          int gm = m0 + wm + mi * 16 + lk * 4 + r;
          float v = acc[mi][ni][r] + bs;
          if (MODE == 0) v = fmaxf(v, 0.f);
          ((unsigned short*)out)[(size_t)gm * N + gn] = f2bf(v);
        }
      }
  }
}

// ---------------- LN1: nattn = LN(O)*g+b (bf16); O unnormalized (LN scale-inv) ----
__global__ __launch_bounds__(256) void k_ln1(const unsigned short* __restrict__ O,
                                             const float* __restrict__ g,
                                             const float* __restrict__ bvec,
                                             unsigned short* __restrict__ nattn) {
  int row = blockIdx.x * 4 + (threadIdx.x >> 6);
  int l = threadIdx.x & 63;
  size_t base = (size_t)row * H_ + l * 8;
  short8 ov = *(const short8*)(O + base);
  float x[8];
#pragma unroll
  for (int i = 0; i < 8; ++i) x[i] = bf2f((unsigned short)ov[i]);
  float s = 0.f, q = 0.f;
#pragma unroll
  for (int i = 0; i < 8; ++i) { s += x[i]; q += x[i] * x[i]; }
#pragma unroll
  for (int m = 1; m < 64; m <<= 1) { s += __shfl_xor(s, m); q += __shfl_xor(q, m); }
  float mean = s * (1.f / 512.f);
  float var = q * (1.f / 512.f) - mean * mean;
  float rstd = rsqrtf(var + 1e-6f);
  f32x4 g0 = *(const f32x4*)(g + l * 8), g1v = *(const f32x4*)(g + l * 8 + 4);
  f32x4 b0 = *(const f32x4*)(bvec + l * 8), b1v = *(const f32x4*)(bvec + l * 8 + 4);
  short8 no;
#pragma unroll
  for (int i = 0; i < 4; ++i) {
    no[i]     = (short)f2bf((x[i] - mean) * rstd * g0[i] + b0[i]);
    no[4 + i] = (short)f2bf((x[4 + i] - mean) * rstd * g1v[i] + b1v[i]);
  }
  *(short8*)(nattn + base) = no;
}

// ---------------- LN2(ff bf16) + nattn + text1 -> out ----------------
__global__ __launch_bounds__(256) void k_ln2(const unsigned short* __restrict__ ff,
                                             const unsigned short* __restrict__ nattn,
                                             const float* __restrict__ text1,
                                             const float* __restrict__ g2,
                                             const float* __restrict__ bb2,
                                             float* __restrict__ out) {
  int row = blockIdx.x * 4 + (threadIdx.x >> 6);
  int l = threadIdx.x & 63;
  size_t base = (size_t)row * H_ + l * 8;
  short8 fv = *(const short8*)(ff + base);
  float x[8];
#pragma unroll
  for (int i = 0; i < 8; ++i) x[i] = bf2f((unsigned short)fv[i]);
  float s = 0.f, q = 0.f;
#pragma unroll
  for (int i = 0; i < 8; ++i) { s += x[i]; q += x[i] * x[i]; }
#pragma unroll
  for (int m = 1; m < 64; m <<= 1) { s += __shfl_xor(s, m); q += __shfl_xor(q, m); }
  float mean = s * (1.f / 512.f);
  float var = q * (1.f / 512.f) - mean * mean;
  float rstd = rsqrtf(var + 1e-6f);
  f32x4 g0 = *(const f32x4*)(g2 + l * 8), g1v = *(const f32x4*)(g2 + l * 8 + 4);
  f32x4 b0 = *(const f32x4*)(bb2 + l * 8), b1v = *(const f32x4*)(bb2 + l * 8 + 4);
  short8 nv = *(const short8*)(nattn + base);
  f32x4 t0 = *(const f32x4*)(text1 + base), t1 = *(const f32x4*)(text1 + base + 4);
  f32x4 o0, o1;
#pragma unroll
  for (int i = 0; i < 4; ++i) {
    o0[i] = (x[i] - mean) * rstd * g0[i] + b0[i] + bf2f((unsigned short)nv[i]) + t0[i];
    o1[i] = (x[4 + i] - mean) * rstd * g1v[i] + b1v[i] + bf2f((unsigned short)nv[4 + i]) + t1[i];
  }
  *(f32x4*)(out + base) = o0;
  *(f32x4*)(out + base + 4) = o1;
}

extern "C" void kernel_launch(void* const* d_in, const int* in_sizes, int n_in,
                              void* d_out, int out_size, void* d_ws, size_t ws_size,
                              hipStream_t stream) {
  const float* text1 = (const float*)d_in[0];
  const float* text2 = (const float*)d_in[1];
  // d_in[2] = text1_mask (unused by reference output)
  const int* mask2 = (const int*)d_in[3];
  const float* W1 = (const float*)d_in[4];
  const float* b1 = (const float*)d_in[5];
  const float* W2 = (const float*)d_in[6];
  const float* b2 = (const float*)d_in[7];
  const float* g1 = (const float*)d_in[8];
  const float* bb1 = (const float*)d_in[9];
  const float* g2 = (const float*)d_in[10];
  const float* bb2 = (const float*)d_in[11];

  const size_t MiB = 1024ull * 1024ull;
  char* ws = (char*)d_ws;
  // ---- layout (max offset 196 MiB) ----
  unsigned short* W1T   = (unsigned short*)(ws + 0 * MiB);          // 1 MiB
  unsigned short* W2T   = (unsigned short*)(ws + 1 * MiB);          // 1 MiB
  unsigned char*  qn8   = (unsigned char*)(ws + 4 * MiB);     // 16 MiB [4,20)
  unsigned char*  kn8   = (unsigned char*)(ws + 20 * MiB);    // 16 MiB [20,36)
  unsigned short* kn    = (unsigned short*)(ws + 36 * MiB);   // 32 MiB [36,68): dead after k_tvt
  unsigned short* vt    = (unsigned short*)(ws + 164 * MiB);  // 32 MiB [164,196): dead after pass2
  unsigned short* P     = (unsigned short*)(ws + 36 * MiB);   // 128 MiB [36,164) over kn (dead);
                                                              //   all 16 batches, dead after pass2
  unsigned short* O     = (unsigned short*)(ws + 4 * MiB);    // 32 MiB [4,36) over qn8+kn8 (dead
                                                              //   after pass1; pass2 runs later)
  // aliases (stream-order lifetimes; each span checked against later readers):
  unsigned short* nattn = (unsigned short*)(ws + 100 * MiB);  // [100,132) over P-mid (dead after
                                                              //   pass2); live LN1 -> LN2; nothing
                                                              //   writes [100,132) in between (FF1
                                                              //   -> [132,196), FF2 -> [36,68)).
  unsigned short* hbuf  = (unsigned short*)(ws + 132 * MiB);  // [132,196) over P-upper + vt (both
                                                              //   dead after pass2)
  unsigned short* ffb   = (unsigned short*)(ws + 36 * MiB);   // [36,68) over P-lower (dead); NOT
                                                              //   overlapping nattn (round-4 bug)
  float* outp = (float*)d_out;

  k_cast<0><<<dim3(B_ * S1_ / 4), 256, 0, stream>>>(text1, nullptr, qn8);
  k_cast<1><<<dim3(B_ * S2_ / 4), 256, 0, stream>>>(text2, kn, kn8);
  k_tw<<<dim3(512 * 1024 / 256), 256, 0, stream>>>(W1, W1T, 9, 1024);
  k_tw<<<dim3(512 * 1024 / 256), 256, 0, stream>>>(W2, W2T, 10, 512);
  k_tvt<<<dim3(H_ / 64, S2_ / 64, B_), 256, 0, stream>>>(kn, vt);

  // pass1 (fp8 pre-normalized, BK=128), all 16 batches: P = exp(q8@k8^T - 1)*mask [SWZ=0]
  k_gemm<2, 0, 1><<<dim3(S2_ / 128, S1_ / 128, B_), 256, 0, stream>>>(
      qn8, kn8, nullptr, mask2,
      P, S1_, S2_, H_, (long)S1_ * H_, (long)S2_ * H_, (long)S1_ * S2_);
  // pass2 (bf16), all 16 batches: O = P @ V (unnormalized; LN1 washes row scale)
  // grid 4x16x16 = 1024 blocks = 4 blk/CU (r9: 512 blocks = 2/CU was the bottleneck)
  k_gemm<3, 1, 0><<<dim3(H_ / 128, S1_ / 128, B_), 256, 0, stream>>>(
      P, vt, nullptr, nullptr,
      O, S1_, H_, S2_, (long)S1_ * S2_ * 2, (long)H_ * S2_ * 2, (long)S1_ * H_);

  k_ln1<<<dim3(B_ * S1_ / 4), 256, 0, stream>>>(O, g1, bb1, nattn);
  k_gemm<0, 1, 0><<<dim3(1024 / 128, 32768 / 128, 1), 256, 0, stream>>>(
      nattn, W1T, b1, nullptr, hbuf, 32768, 1024, 512, 0, 0, 0);
  k_gemm<1, 1, 0><<<dim3(512 / 128, 32768 / 128, 1), 256, 0, stream>>>(
      hbuf, W2T, b2, nullptr, ffb, 32768, 512, 1024, 0, 0, 0);
  k_ln2<<<dim3(32768 / 4), 256, 0, stream>>>(ffb, nattn, text1, g2, bb2, outp);
}